// Round 9
// baseline (473.803 us; speedup 1.0000x reference)
//
#include <hip/hip_runtime.h>
#include <math.h>

#define NN 50000
#define EE 800000
#define GG 1000

typedef __attribute__((ext_vector_type(2))) _Float16 h2f;
typedef __attribute__((ext_vector_type(4))) _Float16 h4f;
typedef __attribute__((ext_vector_type(8))) _Float16 h8f;
typedef __attribute__((ext_vector_type(4))) float f32x4;

#if __has_builtin(__builtin_amdgcn_fdot2)
#define FDOT2(a, b, c) __builtin_amdgcn_fdot2((a), (b), (c), false)
#else
#define FDOT2(a, b, c) ((float)(a)[0] * (float)(b)[0] + (float)(a)[1] * (float)(b)[1] + (c))
#endif

static inline int ceil_div(int a, int b) { return (a + b - 1) / b; }

union EU { int2 i; h4f h; };

// ---------------- counting-sort of edges by dst (packed 16B records) ----------------

__global__ __launch_bounds__(256) void hist_k(const int* __restrict__ ei, int* __restrict__ cnt)
{
    int e = blockIdx.x * 256 + threadIdx.x;
    if (e >= EE) return;
    atomicAdd(&cnt[ei[EE + e]], 1);
}

// scan1 + fused graph-boundary detection (same index domain, independent work)
__global__ __launch_bounds__(1024) void scan1_k(const int* __restrict__ cnt, int n,
                                                int* __restrict__ rowptr, int* __restrict__ bsum,
                                                const int* __restrict__ batch,
                                                int* __restrict__ gptr)
{
    __shared__ int tmp[1024];
    const int tid = threadIdx.x;
    const int i = blockIdx.x * 1024 + tid;
    tmp[tid] = (i < n) ? cnt[i] : 0;
    __syncthreads();
    for (int off = 1; off < 1024; off <<= 1) {
        int t = (tid >= off) ? tmp[tid - off] : 0;
        __syncthreads();
        tmp[tid] += t;
        __syncthreads();
    }
    if (i < n) rowptr[i + 1] = tmp[tid];
    if (tid == 1023) bsum[blockIdx.x] = tmp[1023];
    // fused boundaries (batch is sorted)
    if (i < NN) {
        int b = batch[i];
        int bp = (i == 0) ? -1 : batch[i - 1];
        for (int g = bp + 1; g <= b; ++g) gptr[g] = i;
        if (i == NN - 1) for (int g = b + 1; g <= GG; ++g) gptr[g] = NN;
    }
}

// scan3 with fused cross-block prefix (wave 0 reduces bsum[0..bid-1])
__global__ __launch_bounds__(1024) void scan3_k(int* __restrict__ rowptr,
                                                int* __restrict__ wcur,
                                                const int* __restrict__ bsum, int n)
{
    __shared__ int base_s;
    const int tid = threadIdx.x;
    if (tid < 64) {
        int v = (tid < (int)blockIdx.x) ? bsum[tid] : 0;
#pragma unroll
        for (int off = 1; off < 64; off <<= 1) v += __shfl_xor(v, off);
        if (tid == 0) base_s = v;
    }
    __syncthreads();
    const int base = base_s;
    int i = blockIdx.x * 1024 + tid;
    if (i < n) {
        int v = rowptr[i + 1] + base;
        rowptr[i + 1] = v;
        if (i + 1 < n) wcur[i + 1] = v;
    }
    if (i == 0) { rowptr[0] = 0; wcur[0] = 0; }
}

__global__ __launch_bounds__(256) void scatter_k(const int* __restrict__ ei,
                                                 const float4* __restrict__ ea,
                                                 int* __restrict__ wcur,
                                                 int4* __restrict__ edges)
{
    int e = blockIdx.x * 256 + threadIdx.x;
    if (e >= EE) return;
    int dst = ei[EE + e];
    int pos = atomicAdd(&wcur[dst], 1);
    float4 a = ea[e];
    EU u; u.h = h4f{(_Float16)a.x, (_Float16)a.y, (_Float16)a.z, (_Float16)a.w};
    edges[pos] = make_int4(ei[e], u.i.x, u.i.y, 0);
}

// ---------------- weight shuffle: all 12 matrices in one launch ----------------
struct W12 { const float* w[12]; };

__global__ __launch_bounds__(64) void shuffle_w12(W12 ws, _Float16* __restrict__ out)
{
    const int m = blockIdx.y;
    const int K = (m < 4) ? 64 : 128;
    const int nblk = (K / 16) * 8;
    if (blockIdx.x >= nblk) return;
    const int s = blockIdx.x >> 3, c16 = blockIdx.x & 7;
    const int lane = threadIdx.x;
    const float* __restrict__ w = ws.w[m];
    const int kbase = s * 16 + (lane >> 4) * 4;
    const int col = c16 * 16 + (lane & 15);
    h4f h;
#pragma unroll
    for (int j = 0; j < 4; ++j) h[j] = (_Float16)w[(size_t)(kbase + j) * 128 + col];
    size_t base = (m < 4) ? (size_t)m * 64 * 128
                          : (size_t)4 * 64 * 128 + (size_t)(m - 4) * 128 * 128;
    reinterpret_cast<h4f*>(out + base)[(size_t)blockIdx.x * 64 + lane] = h;
}

// ---------------- fused 4-matrix MFMA GEMM ----------------
// Waves split over OUTPUT-CHANNEL tiles: wave w owns c-tiles {2w,2w+1} x all 64 rows.
// B-frags (x) for 4 row-sets held in registers -> each weight ds_read feeds 4 MFMAs.
template<int K, bool F32IN>
__global__ __launch_bounds__(256) void gemm_mfma(
    const void* __restrict__ xin, const _Float16* __restrict__ wshuf,
    const float* __restrict__ bq, const float* __restrict__ bk,
    const float* __restrict__ bv, const float* __restrict__ bs,
    _Float16* __restrict__ qout, _Float16* __restrict__ kout,
    _Float16* __restrict__ vout, float* __restrict__ skout)
{
    constexpr int KS = K / 16;
    constexpr int PADK = K + 8;
    __shared__ _Float16 xs[64 * PADK];
    __shared__ _Float16 wt[K * 128];
    const int t = threadIdx.x;
    const int bn = blockIdx.x * 64;
    if (F32IN) {
        const float* xf = (const float*)xin;
        constexpr int C4 = K / 4;
        for (int idx = t; idx < 64 * C4; idx += 256) {
            const int row = idx / C4, c4 = idx % C4;
            float4 val = make_float4(0.f, 0.f, 0.f, 0.f);
            if (bn + row < NN)
                val = reinterpret_cast<const float4*>(xf)[(size_t)(bn + row) * C4 + c4];
            h4f h = {(_Float16)val.x, (_Float16)val.y, (_Float16)val.z, (_Float16)val.w};
            *reinterpret_cast<h4f*>(&xs[row * PADK + c4 * 4]) = h;
        }
    } else {
        const _Float16* xh = (const _Float16*)xin;
        constexpr int CH = K / 8;
        for (int idx = t; idx < 64 * CH; idx += 256) {
            const int row = idx / CH, ch = idx % CH;
            h8f val = {0, 0, 0, 0, 0, 0, 0, 0};
            if (bn + row < NN)
                val = reinterpret_cast<const h8f*>(xh + (size_t)(bn + row) * K)[ch];
            *reinterpret_cast<h8f*>(&xs[row * PADK + ch * 8]) = val;
        }
    }
    __syncthreads();

    const int wid = t >> 6, lane = t & 63;
    const int col16 = lane & 15;          // node within row-set (B col / D col)
    const int kq = (lane >> 4) * 4;       // k-quad offset (also D-row quad)
    h4f b[4][KS];
#pragma unroll
    for (int r = 0; r < 4; ++r)
#pragma unroll
        for (int s = 0; s < KS; ++s)
            b[r][s] = *reinterpret_cast<const h4f*>(&xs[(16 * r + col16) * PADK + s * 16 + kq]);

    const float* bias[4] = {bq, bk, bv, bs};
    constexpr int WH4 = K * 32;           // h4f elems per matrix

#pragma unroll
    for (int m = 0; m < 4; ++m) {
        const h4f* __restrict__ wg = reinterpret_cast<const h4f*>(wshuf + (size_t)m * K * 128);
        h4f* __restrict__ wl = reinterpret_cast<h4f*>(wt);
        for (int idx = t; idx < WH4; idx += 256) wl[idx] = wg[idx];
        __syncthreads();

        f32x4 acc[2][4];
#pragma unroll
        for (int cl = 0; cl < 2; ++cl)
#pragma unroll
            for (int r = 0; r < 4; ++r) acc[cl][r] = {0, 0, 0, 0};
#pragma unroll
        for (int cl = 0; cl < 2; ++cl) {
            const int c = wid * 2 + cl;
#pragma unroll
            for (int s = 0; s < KS; ++s) {
                const h4f af = wl[(s * 8 + c) * 64 + lane];
#pragma unroll
                for (int r = 0; r < 4; ++r)
                    acc[cl][r] = __builtin_amdgcn_mfma_f32_16x16x16f16(af, b[r][s], acc[cl][r], 0, 0, 0);
            }
        }
        const float* bm = bias[m];
#pragma unroll
        for (int cl = 0; cl < 2; ++cl) {
            const int hc = (wid * 2 + cl) * 16 + kq;
            const float4 bb = *reinterpret_cast<const float4*>(&bm[hc]);
#pragma unroll
            for (int r = 0; r < 4; ++r) {
                const int node = bn + 16 * r + col16;
                if (node < NN) {
                    float o0 = acc[cl][r][0] + bb.x, o1 = acc[cl][r][1] + bb.y;
                    float o2 = acc[cl][r][2] + bb.z, o3 = acc[cl][r][3] + bb.w;
                    if (m == 3) {
                        *reinterpret_cast<float4*>(&skout[(size_t)node * 128 + hc]) =
                            make_float4(o0, o1, o2, o3);
                    } else {
                        _Float16* dst = (m == 0) ? qout : (m == 1) ? kout : vout;
                        h4f oh = {(_Float16)o0, (_Float16)o1, (_Float16)o2, (_Float16)o3};
                        *reinterpret_cast<h4f*>(&dst[(size_t)node * 128 + hc]) = oh;
                    }
                }
            }
        }
        __syncthreads();
    }
}

// ---------------- fused per-node attention aggregation (unchanged control) ----------------
__global__ __launch_bounds__(256, 8) void node_agg(
    const int* __restrict__ rowptr, const int4* __restrict__ edges,
    const _Float16* __restrict__ qh, const _Float16* __restrict__ kh,
    const _Float16* __restrict__ vh, const float* __restrict__ we,
    const float* __restrict__ sk, _Float16* __restrict__ houth, int relu)
{
    __shared__ float we_s[4 * 128];
    const int t = threadIdx.x;
    if (t < 128)
        reinterpret_cast<float4*>(we_s)[t] = reinterpret_cast<const float4*>(we)[t];
    __syncthreads();
    const int node = blockIdx.x * 4 + (t >> 6);
    if (node >= NN) return;
    const int lane = t & 63;
    const int g = lane >> 4, sub = lane & 15, ch0 = sub * 8;
    const int beg = rowptr[node], end = rowptr[node + 1];
    const int deg = end - beg;

    const float sc = 0.17677669529663687f * 1.4426950408889634f;
    const h8f q8 = *reinterpret_cast<const h8f*>(&qh[(size_t)node * 128 + ch0]);
    float qf[8];
#pragma unroll
    for (int j = 0; j < 8; ++j) qf[j] = (float)q8[j] * sc;
    h2f qp[4];
#pragma unroll
    for (int i = 0; i < 4; ++i) {
        qp[i][0] = (_Float16)qf[2 * i];
        qp[i][1] = (_Float16)qf[2 * i + 1];
    }

    float qe[4];
#pragma unroll
    for (int d = 0; d < 4; ++d) {
        const float4 wa = *reinterpret_cast<const float4*>(&we_s[d * 128 + ch0]);
        const float4 wb = *reinterpret_cast<const float4*>(&we_s[d * 128 + ch0 + 4]);
        float pq = wa.x * qf[0] + wa.y * qf[1] + wa.z * qf[2] + wa.w * qf[3]
                 + wb.x * qf[4] + wb.y * qf[5] + wb.z * qf[6] + wb.w * qf[7];
        pq += __shfl_xor(pq, 1); pq += __shfl_xor(pq, 2);
        qe[d] = pq;
    }

    float m = -1e30f, s = 0.f;
    float acc[8] = {0, 0, 0, 0, 0, 0, 0, 0};
    float T[4] = {0, 0, 0, 0};

    const int nt = (deg + 3) >> 2;
    int p = beg + g;
    for (int i = 0; i < nt; ++i, p += 4) {
        const bool act = p < end;
        const int4 r = edges[act ? p : beg];
        const int4 ki = *reinterpret_cast<const int4*>(&kh[(size_t)r.x * 128 + ch0]);
        const int4 vi = *reinterpret_cast<const int4*>(&vh[(size_t)r.x * 128 + ch0]);
        float al = FDOT2(qp[0], __builtin_bit_cast(h2f, ki.x), 0.0f);
        al = FDOT2(qp[1], __builtin_bit_cast(h2f, ki.y), al);
        al = FDOT2(qp[2], __builtin_bit_cast(h2f, ki.z), al);
        al = FDOT2(qp[3], __builtin_bit_cast(h2f, ki.w), al);
        al += __shfl_xor(al, 1); al += __shfl_xor(al, 2);
        const h2f e01 = __builtin_bit_cast(h2f, r.y);
        const h2f e23 = __builtin_bit_cast(h2f, r.z);
        const float f0 = (float)e01[0], f1 = (float)e01[1];
        const float f2 = (float)e23[0], f3 = (float)e23[1];
        al += f0 * qe[0] + f1 * qe[1] + f2 * qe[2] + f3 * qe[3];
        al = act ? al : -1e30f;
        if (__any(al > m + 10.0f)) {
            const float mn = fmaxf(m, al);
            const float rr = exp2f(m - mn);
            s *= rr;
#pragma unroll
            for (int j = 0; j < 8; ++j) acc[j] *= rr;
#pragma unroll
            for (int d = 0; d < 4; ++d) T[d] *= rr;
            m = mn;
        }
        const float pe = exp2f(al - m);
        s += pe;
        const h2f v01 = __builtin_bit_cast(h2f, vi.x);
        const h2f v23 = __builtin_bit_cast(h2f, vi.y);
        const h2f v45 = __builtin_bit_cast(h2f, vi.z);
        const h2f v67 = __builtin_bit_cast(h2f, vi.w);
        acc[0] += pe * (float)v01[0]; acc[1] += pe * (float)v01[1];
        acc[2] += pe * (float)v23[0]; acc[3] += pe * (float)v23[1];
        acc[4] += pe * (float)v45[0]; acc[5] += pe * (float)v45[1];
        acc[6] += pe * (float)v67[0]; acc[7] += pe * (float)v67[1];
        T[0] += pe * f0; T[1] += pe * f1; T[2] += pe * f2; T[3] += pe * f3;
    }

#pragma unroll
    for (int off = 16; off <= 32; off <<= 1) {
        const float mo = __shfl_xor(m, off);
        const float so = __shfl_xor(s, off);
        const float mn = fmaxf(m, mo);
        const float r1 = exp2f(m - mn), r2 = exp2f(mo - mn);
        s = s * r1 + so * r2;
#pragma unroll
        for (int j = 0; j < 8; ++j) {
            const float ao = __shfl_xor(acc[j], off);
            acc[j] = acc[j] * r1 + ao * r2;
        }
#pragma unroll
        for (int d = 0; d < 4; ++d) {
            const float To = __shfl_xor(T[d], off);
            T[d] = T[d] * r1 + To * r2;
        }
        m = mn;
    }

    if (g == 0) {
        const float inv = 1.0f / (s + 1e-16f);
        float4 wa[4], wb[4];
#pragma unroll
        for (int d = 0; d < 4; ++d) {
            wa[d] = *reinterpret_cast<const float4*>(&we_s[d * 128 + ch0]);
            wb[d] = *reinterpret_cast<const float4*>(&we_s[d * 128 + ch0 + 4]);
        }
        const float4 s0 = *reinterpret_cast<const float4*>(&sk[(size_t)node * 128 + ch0]);
        const float4 s1 = *reinterpret_cast<const float4*>(&sk[(size_t)node * 128 + ch0 + 4]);
        float ov[8];
        ov[0] = (acc[0] + wa[0].x * T[0] + wa[1].x * T[1] + wa[2].x * T[2] + wa[3].x * T[3]) * inv + s0.x;
        ov[1] = (acc[1] + wa[0].y * T[0] + wa[1].y * T[1] + wa[2].y * T[2] + wa[3].y * T[3]) * inv + s0.y;
        ov[2] = (acc[2] + wa[0].z * T[0] + wa[1].z * T[1] + wa[2].z * T[2] + wa[3].z * T[3]) * inv + s0.z;
        ov[3] = (acc[3] + wa[0].w * T[0] + wa[1].w * T[1] + wa[2].w * T[2] + wa[3].w * T[3]) * inv + s0.w;
        ov[4] = (acc[4] + wb[0].x * T[0] + wb[1].x * T[1] + wb[2].x * T[2] + wb[3].x * T[3]) * inv + s1.x;
        ov[5] = (acc[5] + wb[0].y * T[0] + wb[1].y * T[1] + wb[2].y * T[2] + wb[3].y * T[3]) * inv + s1.y;
        ov[6] = (acc[6] + wb[0].z * T[0] + wb[1].z * T[1] + wb[2].z * T[2] + wb[3].z * T[3]) * inv + s1.z;
        ov[7] = (acc[7] + wb[0].w * T[0] + wb[1].w * T[1] + wb[2].w * T[2] + wb[3].w * T[3]) * inv + s1.w;
        h8f oh;
#pragma unroll
        for (int j = 0; j < 8; ++j) {
            float v = relu ? fmaxf(ov[j], 0.f) : ov[j];
            oh[j] = (_Float16)v;
        }
        *reinterpret_cast<h8f*>(&houth[(size_t)node * 128 + ch0]) = oh;
    }
}

// ---------------- pooling + head (batch is sorted; h in f16) ----------------

__global__ __launch_bounds__(128) void head_k(
    const _Float16* __restrict__ h, const int* __restrict__ gptr,
    const float* __restrict__ wlin, const float* __restrict__ blin,
    float* __restrict__ out)
{
    __shared__ float red[128];
    const int g = blockIdx.x;
    const int t = threadIdx.x;
    const int beg = gptr[g], end = gptr[g + 1];
    float p = 0.f;
    for (int n = beg; n < end; ++n) p += (float)h[(size_t)n * 128 + t];
    p *= wlin[t];
    red[t] = p;
    __syncthreads();
    for (int off = 64; off; off >>= 1) {
        if (t < off) red[t] += red[t + off];
        __syncthreads();
    }
    if (t == 0) out[g] = red[0] / fmaxf((float)(end - beg), 1.0f) + blin[0];
}

extern "C" void kernel_launch(void* const* d_in, const int* in_sizes, int n_in,
                              void* d_out, int out_size, void* d_ws, size_t ws_size,
                              hipStream_t stream)
{
    const float* x     = (const float*)d_in[0];
    const int*   ei    = (const int*)d_in[1];
    const float* ea    = (const float*)d_in[2];
    const int*   batch = (const int*)d_in[3];
    auto W = [&](int i) { return (const float*)d_in[i]; };

    char* wsb = (char*)d_ws;
    size_t off = 0;
    auto alloc = [&](size_t bytes) { void* p = wsb + off; off += (bytes + 15) & ~15ull; return p; };

    float* sk       = (float*)alloc((size_t)NN * 128 * 4);
    int4*  edges    = (int4*)alloc((size_t)EE * 16);
    _Float16* qh    = (_Float16*)alloc((size_t)NN * 128 * 2);
    _Float16* kh    = (_Float16*)alloc((size_t)NN * 128 * 2);
    _Float16* vh    = (_Float16*)alloc((size_t)NN * 128 * 2);
    _Float16* hh    = (_Float16*)alloc((size_t)NN * 128 * 2);
    _Float16* wshuf = (_Float16*)alloc(((size_t)4 * 64 * 128 + 8 * 128 * 128) * 2);
    int* cnt    = (int*)alloc((size_t)NN * 4);
    int* rowptr = (int*)alloc((size_t)(NN + 1) * 4);
    int* wcur   = (int*)alloc((size_t)NN * 4);
    int* gptr   = (int*)alloc((size_t)(GG + 1) * 4);
    int* bsum   = (int*)alloc((size_t)64 * 4);

    // ---- CSR build + packed edge records (recomputed each call; deterministic) ----
    hipMemsetAsync(cnt, 0, NN * sizeof(int), stream);
    hist_k<<<ceil_div(EE, 256), 256, 0, stream>>>(ei, cnt);
    const int NB = ceil_div(NN, 1024);
    scan1_k<<<NB, 1024, 0, stream>>>(cnt, NN, rowptr, bsum, batch, gptr);
    scan3_k<<<NB, 1024, 0, stream>>>(rowptr, wcur, bsum, NN);
    scatter_k<<<ceil_div(EE, 256), 256, 0, stream>>>(ei, (const float4*)ea, wcur, edges);

    W12 w12 = {{ W(4), W(6), W(8), W(11),
                 W(13), W(15), W(17), W(20),
                 W(22), W(24), W(26), W(29) }};
    shuffle_w12<<<dim3(64, 12), 64, 0, stream>>>(w12, wshuf);
    const size_t wsz1 = (size_t)4 * 64 * 128;
    const size_t wsz2 = (size_t)4 * 128 * 128;

    auto layer = [&](int K, const void* xin, const _Float16* wsh, int relu, int wb) {
        if (K == 64)
            gemm_mfma<64, true><<<ceil_div(NN, 64), 256, 0, stream>>>(
                xin, wsh, W(wb + 1), W(wb + 3), W(wb + 5), W(wb + 8), qh, kh, vh, sk);
        else
            gemm_mfma<128, false><<<ceil_div(NN, 64), 256, 0, stream>>>(
                xin, wsh, W(wb + 1), W(wb + 3), W(wb + 5), W(wb + 8), qh, kh, vh, sk);
        node_agg<<<ceil_div(NN, 4), 256, 0, stream>>>(
            rowptr, edges, qh, kh, vh, W(wb + 6), sk, hh, relu);
    };

    layer(64,  x,  wshuf, 1, 4);
    layer(128, hh, wshuf + wsz1, 1, 13);
    layer(128, hh, wshuf + wsz1 + wsz2, 0, 22);

    head_k<<<GG, 128, 0, stream>>>(hh, gptr, W(31), W(32), (float*)d_out);
}

// Round 13
// 461.907 us; speedup vs baseline: 1.0258x; 1.0258x over previous
//
#include <hip/hip_runtime.h>
#include <math.h>

#define NN 50000
#define EE 800000
#define GG 1000

typedef __attribute__((ext_vector_type(2))) _Float16 h2f;
typedef __attribute__((ext_vector_type(4))) _Float16 h4f;
typedef __attribute__((ext_vector_type(8))) _Float16 h8f;
typedef __attribute__((ext_vector_type(4))) float f32x4;

#if __has_builtin(__builtin_amdgcn_fdot2)
#define FDOT2(a, b, c) __builtin_amdgcn_fdot2((a), (b), (c), false)
#else
#define FDOT2(a, b, c) ((float)(a)[0] * (float)(b)[0] + (float)(a)[1] * (float)(b)[1] + (c))
#endif

static inline int ceil_div(int a, int b) { return (a + b - 1) / b; }

union EU { int2 i; h4f h; };

// ---------------- counting-sort of edges by dst (packed 16B records) ----------------

__global__ __launch_bounds__(256) void hist_k(const int* __restrict__ ei, int* __restrict__ cnt)
{
    int e = blockIdx.x * 256 + threadIdx.x;
    if (e >= EE) return;
    atomicAdd(&cnt[ei[EE + e]], 1);
}

// scan1 + fused graph-boundary detection (ran green in round 9)
__global__ __launch_bounds__(1024) void scan1_k(const int* __restrict__ cnt, int n,
                                                int* __restrict__ rowptr, int* __restrict__ bsum,
                                                const int* __restrict__ batch,
                                                int* __restrict__ gptr)
{
    __shared__ int tmp[1024];
    const int tid = threadIdx.x;
    const int i = blockIdx.x * 1024 + tid;
    tmp[tid] = (i < n) ? cnt[i] : 0;
    __syncthreads();
    for (int off = 1; off < 1024; off <<= 1) {
        int t = (tid >= off) ? tmp[tid - off] : 0;
        __syncthreads();
        tmp[tid] += t;
        __syncthreads();
    }
    if (i < n) rowptr[i + 1] = tmp[tid];
    if (tid == 1023) bsum[blockIdx.x] = tmp[1023];
    if (i < NN) {
        int b = batch[i];
        int bp = (i == 0) ? -1 : batch[i - 1];
        for (int g = bp + 1; g <= b; ++g) gptr[g] = i;
        if (i == NN - 1) for (int g = b + 1; g <= GG; ++g) gptr[g] = NN;
    }
}

// scan3 with fused cross-block prefix (ran green in round 9)
__global__ __launch_bounds__(1024) void scan3_k(int* __restrict__ rowptr,
                                                int* __restrict__ wcur,
                                                const int* __restrict__ bsum, int n)
{
    __shared__ int base_s;
    const int tid = threadIdx.x;
    if (tid < 64) {
        int v = (tid < (int)blockIdx.x) ? bsum[tid] : 0;
#pragma unroll
        for (int off = 1; off < 64; off <<= 1) v += __shfl_xor(v, off);
        if (tid == 0) base_s = v;
    }
    __syncthreads();
    const int base = base_s;
    int i = blockIdx.x * 1024 + tid;
    if (i < n) {
        int v = rowptr[i + 1] + base;
        rowptr[i + 1] = v;
        if (i + 1 < n) wcur[i + 1] = v;
    }
    if (i == 0) { rowptr[0] = 0; wcur[0] = 0; }
}

__global__ __launch_bounds__(256) void scatter_k(const int* __restrict__ ei,
                                                 const float4* __restrict__ ea,
                                                 int* __restrict__ wcur,
                                                 int4* __restrict__ edges)
{
    int e = blockIdx.x * 256 + threadIdx.x;
    if (e >= EE) return;
    int dst = ei[EE + e];
    int pos = atomicAdd(&wcur[dst], 1);
    float4 a = ea[e];
    EU u; u.h = h4f{(_Float16)a.x, (_Float16)a.y, (_Float16)a.z, (_Float16)a.w};
    edges[pos] = make_int4(ei[e], u.i.x, u.i.y, 0);
}

// ---------------- weight shuffle: all 12 matrices in one launch ----------------
struct W12 { const float* w[12]; };

__global__ __launch_bounds__(64) void shuffle_w12(W12 ws, _Float16* __restrict__ out)
{
    const int m = blockIdx.y;
    const int K = (m < 4) ? 64 : 128;
    const int nblk = (K / 16) * 8;
    if (blockIdx.x >= nblk) return;
    const int s = blockIdx.x >> 3, c16 = blockIdx.x & 7;
    const int lane = threadIdx.x;
    const float* __restrict__ w = ws.w[m];
    const int kbase = s * 16 + (lane >> 4) * 4;
    const int col = c16 * 16 + (lane & 15);
    h4f h;
#pragma unroll
    for (int j = 0; j < 4; ++j) h[j] = (_Float16)w[(size_t)(kbase + j) * 128 + col];
    size_t base = (m < 4) ? (size_t)m * 64 * 128
                          : (size_t)4 * 64 * 128 + (size_t)(m - 4) * 128 * 128;
    reinterpret_cast<h4f*>(out + base)[(size_t)blockIdx.x * 64 + lane] = h;
}

// ---------------- fused 4-matrix MFMA GEMM (round-8 structure; sk now f16) ----------------
template<int K, bool F32IN>
__global__ __launch_bounds__(256) void gemm_mfma(
    const void* __restrict__ xin, const _Float16* __restrict__ wshuf,
    const float* __restrict__ bq, const float* __restrict__ bk,
    const float* __restrict__ bv, const float* __restrict__ bs,
    _Float16* __restrict__ qout, _Float16* __restrict__ kout,
    _Float16* __restrict__ vout, _Float16* __restrict__ skout)
{
    constexpr int KS = K / 16;
    constexpr int PADK = K + 8;
    __shared__ _Float16 xs[64 * PADK];
    __shared__ _Float16 wt[K * 128];
    const int t = threadIdx.x;
    const int bn = blockIdx.x * 64;
    if (F32IN) {
        const float* xf = (const float*)xin;
        constexpr int C4 = K / 4;
        for (int idx = t; idx < 64 * C4; idx += 256) {
            const int row = idx / C4, c4 = idx % C4;
            float4 val = make_float4(0.f, 0.f, 0.f, 0.f);
            if (bn + row < NN)
                val = reinterpret_cast<const float4*>(xf)[(size_t)(bn + row) * C4 + c4];
            h4f h = {(_Float16)val.x, (_Float16)val.y, (_Float16)val.z, (_Float16)val.w};
            *reinterpret_cast<h4f*>(&xs[row * PADK + c4 * 4]) = h;
        }
    } else {
        const _Float16* xh = (const _Float16*)xin;
        constexpr int CH = K / 8;
        for (int idx = t; idx < 64 * CH; idx += 256) {
            const int row = idx / CH, ch = idx % CH;
            h8f val = {0, 0, 0, 0, 0, 0, 0, 0};
            if (bn + row < NN)
                val = reinterpret_cast<const h8f*>(xh + (size_t)(bn + row) * K)[ch];
            *reinterpret_cast<h8f*>(&xs[row * PADK + ch * 8]) = val;
        }
    }
    __syncthreads();

    const int wid = t >> 6, lane = t & 63;
    const int rloc = wid * 16 + (lane & 15);
    const int ko = (lane >> 4) * 4;
    h4f b[KS];
#pragma unroll
    for (int s = 0; s < KS; ++s)
        b[s] = *reinterpret_cast<const h4f*>(&xs[rloc * PADK + s * 16 + ko]);

    const int node = bn + rloc;
    const int hcq = (lane >> 4) * 4;
    const float* bias[4] = {bq, bk, bv, bs};
    constexpr int WH4 = K * 32;

#pragma unroll
    for (int m = 0; m < 4; ++m) {
        const h4f* __restrict__ wg = reinterpret_cast<const h4f*>(wshuf + (size_t)m * K * 128);
        h4f* __restrict__ wl = reinterpret_cast<h4f*>(wt);
        for (int idx = t; idx < WH4; idx += 256) wl[idx] = wg[idx];
        __syncthreads();

        f32x4 acc[8];
#pragma unroll
        for (int c = 0; c < 8; ++c) acc[c] = {0, 0, 0, 0};
#pragma unroll
        for (int c = 0; c < 8; ++c)
#pragma unroll
            for (int s = 0; s < KS; ++s) {
                h4f af = wl[(s * 8 + c) * 64 + lane];
                acc[c] = __builtin_amdgcn_mfma_f32_16x16x16f16(af, b[s], acc[c], 0, 0, 0);
            }
        if (node < NN) {
            const float* bm = bias[m];
#pragma unroll
            for (int c = 0; c < 8; ++c) {
                const int hc = c * 16 + hcq;
                const float4 bb = *reinterpret_cast<const float4*>(&bm[hc]);
                float o0 = acc[c][0] + bb.x, o1 = acc[c][1] + bb.y;
                float o2 = acc[c][2] + bb.z, o3 = acc[c][3] + bb.w;
                if (m == 0) {
                    h4f oh = {(_Float16)o0, (_Float16)o1, (_Float16)o2, (_Float16)o3};
                    *reinterpret_cast<h4f*>(&qout[(size_t)node * 128 + hc]) = oh;
                } else if (m == 1) {
                    h4f oh = {(_Float16)o0, (_Float16)o1, (_Float16)o2, (_Float16)o3};
                    *reinterpret_cast<h4f*>(&kout[(size_t)node * 128 + hc]) = oh;
                } else if (m == 2) {
                    h4f oh = {(_Float16)o0, (_Float16)o1, (_Float16)o2, (_Float16)o3};
                    *reinterpret_cast<h4f*>(&vout[(size_t)node * 128 + hc]) = oh;
                } else {
                    h4f oh = {(_Float16)o0, (_Float16)o1, (_Float16)o2, (_Float16)o3};
                    *reinterpret_cast<h4f*>(&skout[(size_t)node * 128 + hc]) = oh;
                }
            }
        }
        __syncthreads();
    }
}

// ---------------- fused per-node attention aggregation (round-8 version; sk f16) ----------------
__global__ __launch_bounds__(256, 8) void node_agg(
    const int* __restrict__ rowptr, const int4* __restrict__ edges,
    const _Float16* __restrict__ qh, const _Float16* __restrict__ kh,
    const _Float16* __restrict__ vh, const float* __restrict__ we,
    const _Float16* __restrict__ sk, _Float16* __restrict__ houth, int relu)
{
    __shared__ float we_s[4 * 128];
    const int t = threadIdx.x;
    if (t < 128)
        reinterpret_cast<float4*>(we_s)[t] = reinterpret_cast<const float4*>(we)[t];
    __syncthreads();
    const int node = blockIdx.x * 4 + (t >> 6);
    if (node >= NN) return;
    const int lane = t & 63;
    const int g = lane >> 4, sub = lane & 15, ch0 = sub * 8;
    const int beg = rowptr[node], end = rowptr[node + 1];
    const int deg = end - beg;

    // q scaled in-kernel by (1/sqrt(32))*log2(e)  (round-8 behavior)
    const float sc = 0.17677669529663687f * 1.4426950408889634f;
    const h8f q8 = *reinterpret_cast<const h8f*>(&qh[(size_t)node * 128 + ch0]);
    float qf[8];
#pragma unroll
    for (int j = 0; j < 8; ++j) qf[j] = (float)q8[j] * sc;
    h2f qp[4];
#pragma unroll
    for (int i = 0; i < 4; ++i) {
        qp[i][0] = (_Float16)qf[2 * i];
        qp[i][1] = (_Float16)qf[2 * i + 1];
    }

    float qe[4];
#pragma unroll
    for (int d = 0; d < 4; ++d) {
        const float4 wa = *reinterpret_cast<const float4*>(&we_s[d * 128 + ch0]);
        const float4 wb = *reinterpret_cast<const float4*>(&we_s[d * 128 + ch0 + 4]);
        float pq = wa.x * qf[0] + wa.y * qf[1] + wa.z * qf[2] + wa.w * qf[3]
                 + wb.x * qf[4] + wb.y * qf[5] + wb.z * qf[6] + wb.w * qf[7];
        pq += __shfl_xor(pq, 1); pq += __shfl_xor(pq, 2);
        qe[d] = pq;
    }

    float m = -1e30f, s = 0.f;
    float acc[8] = {0, 0, 0, 0, 0, 0, 0, 0};
    float T[4] = {0, 0, 0, 0};

    const int nt = (deg + 3) >> 2;
    int p = beg + g;
    for (int i = 0; i < nt; ++i, p += 4) {
        const bool act = p < end;
        const int4 r = edges[act ? p : beg];
        const int4 ki = *reinterpret_cast<const int4*>(&kh[(size_t)r.x * 128 + ch0]);
        const int4 vi = *reinterpret_cast<const int4*>(&vh[(size_t)r.x * 128 + ch0]);
        float al = FDOT2(qp[0], __builtin_bit_cast(h2f, ki.x), 0.0f);
        al = FDOT2(qp[1], __builtin_bit_cast(h2f, ki.y), al);
        al = FDOT2(qp[2], __builtin_bit_cast(h2f, ki.z), al);
        al = FDOT2(qp[3], __builtin_bit_cast(h2f, ki.w), al);
        al += __shfl_xor(al, 1); al += __shfl_xor(al, 2);   // 4-lane head reduce
        const h2f e01 = __builtin_bit_cast(h2f, r.y);
        const h2f e23 = __builtin_bit_cast(h2f, r.z);
        const float f0 = (float)e01[0], f1 = (float)e01[1];
        const float f2 = (float)e23[0], f3 = (float)e23[1];
        al += f0 * qe[0] + f1 * qe[1] + f2 * qe[2] + f3 * qe[3];
        al = act ? al : -1e30f;
        if (__any(al > m + 10.0f)) {
            const float mn = fmaxf(m, al);
            const float rr = exp2f(m - mn);
            s *= rr;
#pragma unroll
            for (int j = 0; j < 8; ++j) acc[j] *= rr;
#pragma unroll
            for (int d = 0; d < 4; ++d) T[d] *= rr;
            m = mn;
        }
        const float pe = exp2f(al - m);
        s += pe;
        const h2f v01 = __builtin_bit_cast(h2f, vi.x);
        const h2f v23 = __builtin_bit_cast(h2f, vi.y);
        const h2f v45 = __builtin_bit_cast(h2f, vi.z);
        const h2f v67 = __builtin_bit_cast(h2f, vi.w);
        acc[0] += pe * (float)v01[0]; acc[1] += pe * (float)v01[1];
        acc[2] += pe * (float)v23[0]; acc[3] += pe * (float)v23[1];
        acc[4] += pe * (float)v45[0]; acc[5] += pe * (float)v45[1];
        acc[6] += pe * (float)v67[0]; acc[7] += pe * (float)v67[1];
        T[0] += pe * f0; T[1] += pe * f1; T[2] += pe * f2; T[3] += pe * f3;
    }

    // merge the 4 group states (exact split-softmax merge)
#pragma unroll
    for (int off = 16; off <= 32; off <<= 1) {
        const float mo = __shfl_xor(m, off);
        const float so = __shfl_xor(s, off);
        const float mn = fmaxf(m, mo);
        const float r1 = exp2f(m - mn), r2 = exp2f(mo - mn);
        s = s * r1 + so * r2;
#pragma unroll
        for (int j = 0; j < 8; ++j) {
            const float ao = __shfl_xor(acc[j], off);
            acc[j] = acc[j] * r1 + ao * r2;
        }
#pragma unroll
        for (int d = 0; d < 4; ++d) {
            const float To = __shfl_xor(T[d], off);
            T[d] = T[d] * r1 + To * r2;
        }
        m = mn;
    }

    if (g == 0) {
        const float inv = 1.0f / (s + 1e-16f);
        float4 wa[4], wb[4];
#pragma unroll
        for (int d = 0; d < 4; ++d) {
            wa[d] = *reinterpret_cast<const float4*>(&we_s[d * 128 + ch0]);
            wb[d] = *reinterpret_cast<const float4*>(&we_s[d * 128 + ch0 + 4]);
        }
        const h8f sk8 = *reinterpret_cast<const h8f*>(&sk[(size_t)node * 128 + ch0]);
        float ov[8];
        ov[0] = (acc[0] + wa[0].x * T[0] + wa[1].x * T[1] + wa[2].x * T[2] + wa[3].x * T[3]) * inv + (float)sk8[0];
        ov[1] = (acc[1] + wa[0].y * T[0] + wa[1].y * T[1] + wa[2].y * T[2] + wa[3].y * T[3]) * inv + (float)sk8[1];
        ov[2] = (acc[2] + wa[0].z * T[0] + wa[1].z * T[1] + wa[2].z * T[2] + wa[3].z * T[3]) * inv + (float)sk8[2];
        ov[3] = (acc[3] + wa[0].w * T[0] + wa[1].w * T[1] + wa[2].w * T[2] + wa[3].w * T[3]) * inv + (float)sk8[3];
        ov[4] = (acc[4] + wb[0].x * T[0] + wb[1].x * T[1] + wb[2].x * T[2] + wb[3].x * T[3]) * inv + (float)sk8[4];
        ov[5] = (acc[5] + wb[0].y * T[0] + wb[1].y * T[1] + wb[2].y * T[2] + wb[3].y * T[3]) * inv + (float)sk8[5];
        ov[6] = (acc[6] + wb[0].z * T[0] + wb[1].z * T[1] + wb[2].z * T[2] + wb[3].z * T[3]) * inv + (float)sk8[6];
        ov[7] = (acc[7] + wb[0].w * T[0] + wb[1].w * T[1] + wb[2].w * T[2] + wb[3].w * T[3]) * inv + (float)sk8[7];
        h8f oh;
#pragma unroll
        for (int j = 0; j < 8; ++j) {
            float v = relu ? fmaxf(ov[j], 0.f) : ov[j];
            oh[j] = (_Float16)v;
        }
        *reinterpret_cast<h8f*>(&houth[(size_t)node * 128 + ch0]) = oh;
    }
}

// ---------------- pooling + head (batch is sorted; h in f16) ----------------

__global__ __launch_bounds__(128) void head_k(
    const _Float16* __restrict__ h, const int* __restrict__ gptr,
    const float* __restrict__ wlin, const float* __restrict__ blin,
    float* __restrict__ out)
{
    __shared__ float red[128];
    const int g = blockIdx.x;
    const int t = threadIdx.x;
    const int beg = gptr[g], end = gptr[g + 1];
    float p = 0.f;
    for (int n = beg; n < end; ++n) p += (float)h[(size_t)n * 128 + t];
    p *= wlin[t];
    red[t] = p;
    __syncthreads();
    for (int off = 64; off; off >>= 1) {
        if (t < off) red[t] += red[t + off];
        __syncthreads();
    }
    if (t == 0) out[g] = red[0] / fmaxf((float)(end - beg), 1.0f) + blin[0];
}

extern "C" void kernel_launch(void* const* d_in, const int* in_sizes, int n_in,
                              void* d_out, int out_size, void* d_ws, size_t ws_size,
                              hipStream_t stream)
{
    const float* x     = (const float*)d_in[0];
    const int*   ei    = (const int*)d_in[1];
    const float* ea    = (const float*)d_in[2];
    const int*   batch = (const int*)d_in[3];
    auto W = [&](int i) { return (const float*)d_in[i]; };

    char* wsb = (char*)d_ws;
    size_t off = 0;
    auto alloc = [&](size_t bytes) { void* p = wsb + off; off += (bytes + 15) & ~15ull; return p; };

    int4*  edges    = (int4*)alloc((size_t)EE * 16);
    _Float16* qh    = (_Float16*)alloc((size_t)NN * 128 * 2);
    _Float16* kh    = (_Float16*)alloc((size_t)NN * 128 * 2);
    _Float16* vh    = (_Float16*)alloc((size_t)NN * 128 * 2);
    _Float16* sk    = (_Float16*)alloc((size_t)NN * 128 * 2);
    _Float16* hh    = (_Float16*)alloc((size_t)NN * 128 * 2);
    _Float16* wshuf = (_Float16*)alloc(((size_t)4 * 64 * 128 + 8 * 128 * 128) * 2);
    int* cnt    = (int*)alloc((size_t)NN * 4);
    int* rowptr = (int*)alloc((size_t)(NN + 1) * 4);
    int* wcur   = (int*)alloc((size_t)NN * 4);
    int* gptr   = (int*)alloc((size_t)(GG + 1) * 4);
    int* bsum   = (int*)alloc((size_t)64 * 4);

    // ---- CSR build + packed edge records (recomputed each call; deterministic) ----
    hipMemsetAsync(cnt, 0, NN * sizeof(int), stream);
    hist_k<<<ceil_div(EE, 256), 256, 0, stream>>>(ei, cnt);
    const int NB = ceil_div(NN, 1024);
    scan1_k<<<NB, 1024, 0, stream>>>(cnt, NN, rowptr, bsum, batch, gptr);
    scan3_k<<<NB, 1024, 0, stream>>>(rowptr, wcur, bsum, NN);
    scatter_k<<<ceil_div(EE, 256), 256, 0, stream>>>(ei, (const float4*)ea, wcur, edges);

    W12 w12 = {{ W(4), W(6), W(8), W(11),
                 W(13), W(15), W(17), W(20),
                 W(22), W(24), W(26), W(29) }};
    shuffle_w12<<<dim3(64, 12), 64, 0, stream>>>(w12, wshuf);
    const size_t wsz1 = (size_t)4 * 64 * 128;
    const size_t wsz2 = (size_t)4 * 128 * 128;

    auto layer = [&](int K, const void* xin, const _Float16* wsh, int relu, int wb) {
        if (K == 64)
            gemm_mfma<64, true><<<ceil_div(NN, 64), 256, 0, stream>>>(
                xin, wsh, W(wb + 1), W(wb + 3), W(wb + 5), W(wb + 8), qh, kh, vh, sk);
        else
            gemm_mfma<128, false><<<ceil_div(NN, 64), 256, 0, stream>>>(
                xin, wsh, W(wb + 1), W(wb + 3), W(wb + 5), W(wb + 8), qh, kh, vh, sk);
        node_agg<<<ceil_div(NN, 4), 256, 0, stream>>>(
            rowptr, edges, qh, kh, vh, W(wb + 6), sk, hh, relu);
    };

    layer(64,  x,  wshuf, 1, 4);
    layer(128, hh, wshuf + wsz1, 1, 13);
    layer(128, hh, wshuf + wsz1 + wsz2, 0, 22);

    head_k<<<GG, 128, 0, stream>>>(hh, gptr, W(31), W(32), (float*)d_out);
}

// Round 14
// 417.699 us; speedup vs baseline: 1.1343x; 1.1058x over previous
//
#include <hip/hip_runtime.h>
#include <math.h>

#define NN 50000
#define EE 800000
#define GG 1000

typedef __attribute__((ext_vector_type(2))) _Float16 h2f;
typedef __attribute__((ext_vector_type(4))) _Float16 h4f;
typedef __attribute__((ext_vector_type(8))) _Float16 h8f;
typedef __attribute__((ext_vector_type(4))) float f32x4;

#if __has_builtin(__builtin_amdgcn_fdot2)
#define FDOT2(a, b, c) __builtin_amdgcn_fdot2((a), (b), (c), false)
#else
#define FDOT2(a, b, c) ((float)(a)[0] * (float)(b)[0] + (float)(a)[1] * (float)(b)[1] + (c))
#endif

static inline int ceil_div(int a, int b) { return (a + b - 1) / b; }

union EU { int2 i; h4f h; };

// ---------------- counting-sort of edges by dst (packed 16B records) ----------------

__global__ __launch_bounds__(256) void hist_k(const int* __restrict__ ei, int* __restrict__ cnt)
{
    int e = blockIdx.x * 256 + threadIdx.x;
    if (e >= EE) return;
    atomicAdd(&cnt[ei[EE + e]], 1);
}

// scan1 + fused graph-boundary detection
__global__ __launch_bounds__(1024) void scan1_k(const int* __restrict__ cnt, int n,
                                                int* __restrict__ rowptr, int* __restrict__ bsum,
                                                const int* __restrict__ batch,
                                                int* __restrict__ gptr)
{
    __shared__ int tmp[1024];
    const int tid = threadIdx.x;
    const int i = blockIdx.x * 1024 + tid;
    tmp[tid] = (i < n) ? cnt[i] : 0;
    __syncthreads();
    for (int off = 1; off < 1024; off <<= 1) {
        int t = (tid >= off) ? tmp[tid - off] : 0;
        __syncthreads();
        tmp[tid] += t;
        __syncthreads();
    }
    if (i < n) rowptr[i + 1] = tmp[tid];
    if (tid == 1023) bsum[blockIdx.x] = tmp[1023];
    if (i < NN) {
        int b = batch[i];
        int bp = (i == 0) ? -1 : batch[i - 1];
        for (int g = bp + 1; g <= b; ++g) gptr[g] = i;
        if (i == NN - 1) for (int g = b + 1; g <= GG; ++g) gptr[g] = NN;
    }
}

// scan3 with fused cross-block prefix
__global__ __launch_bounds__(1024) void scan3_k(int* __restrict__ rowptr,
                                                int* __restrict__ wcur,
                                                const int* __restrict__ bsum, int n)
{
    __shared__ int base_s;
    const int tid = threadIdx.x;
    if (tid < 64) {
        int v = (tid < (int)blockIdx.x) ? bsum[tid] : 0;
#pragma unroll
        for (int off = 1; off < 64; off <<= 1) v += __shfl_xor(v, off);
        if (tid == 0) base_s = v;
    }
    __syncthreads();
    const int base = base_s;
    int i = blockIdx.x * 1024 + tid;
    if (i < n) {
        int v = rowptr[i + 1] + base;
        rowptr[i + 1] = v;
        if (i + 1 < n) wcur[i + 1] = v;
    }
    if (i == 0) { rowptr[0] = 0; wcur[0] = 0; }
}

__global__ __launch_bounds__(256) void scatter_k(const int* __restrict__ ei,
                                                 const float4* __restrict__ ea,
                                                 int* __restrict__ wcur,
                                                 int4* __restrict__ edges)
{
    int e = blockIdx.x * 256 + threadIdx.x;
    if (e >= EE) return;
    int dst = ei[EE + e];
    int pos = atomicAdd(&wcur[dst], 1);
    float4 a = ea[e];
    EU u; u.h = h4f{(_Float16)a.x, (_Float16)a.y, (_Float16)a.z, (_Float16)a.w};
    edges[pos] = make_int4(ei[e], u.i.x, u.i.y, 0);
}

// ---------------- weight shuffle: all 12 matrices in one launch ----------------
struct W12 { const float* w[12]; };

__global__ __launch_bounds__(64) void shuffle_w12(W12 ws, _Float16* __restrict__ out)
{
    const int m = blockIdx.y;
    const int K = (m < 4) ? 64 : 128;
    const int nblk = (K / 16) * 8;
    if (blockIdx.x >= nblk) return;
    const int s = blockIdx.x >> 3, c16 = blockIdx.x & 7;
    const int lane = threadIdx.x;
    const float* __restrict__ w = ws.w[m];
    const int kbase = s * 16 + (lane >> 4) * 4;
    const int col = c16 * 16 + (lane & 15);
    h4f h;
#pragma unroll
    for (int j = 0; j < 4; ++j) h[j] = (_Float16)w[(size_t)(kbase + j) * 128 + col];
    size_t base = (m < 4) ? (size_t)m * 64 * 128
                          : (size_t)4 * 64 * 128 + (size_t)(m - 4) * 128 * 128;
    reinterpret_cast<h4f*>(out + base)[(size_t)blockIdx.x * 64 + lane] = h;
}

// ---------------- MFMA GEMM: one matrix per blockIdx.y ----------------
// Each block: stage x-tile + ONE weight matrix (2 barriers), compute, store.
template<int K, bool F32IN>
__global__ __launch_bounds__(256) void gemm_mfma(
    const void* __restrict__ xin, const _Float16* __restrict__ wshuf,
    const float* __restrict__ bq, const float* __restrict__ bk,
    const float* __restrict__ bv, const float* __restrict__ bs,
    _Float16* __restrict__ qout, _Float16* __restrict__ kout,
    _Float16* __restrict__ vout, _Float16* __restrict__ skout)
{
    constexpr int KS = K / 16;
    constexpr int PADK = K + 8;
    __shared__ _Float16 xs[64 * PADK];
    __shared__ _Float16 wt[K * 128];
    const int t = threadIdx.x;
    const int bn = blockIdx.x * 64;
    const int m = blockIdx.y;

    // stage x tile
    if (F32IN) {
        const float* xf = (const float*)xin;
        constexpr int C4 = K / 4;
        for (int idx = t; idx < 64 * C4; idx += 256) {
            const int row = idx / C4, c4 = idx % C4;
            float4 val = make_float4(0.f, 0.f, 0.f, 0.f);
            if (bn + row < NN)
                val = reinterpret_cast<const float4*>(xf)[(size_t)(bn + row) * C4 + c4];
            h4f h = {(_Float16)val.x, (_Float16)val.y, (_Float16)val.z, (_Float16)val.w};
            *reinterpret_cast<h4f*>(&xs[row * PADK + c4 * 4]) = h;
        }
    } else {
        const _Float16* xh = (const _Float16*)xin;
        constexpr int CH = K / 8;
        for (int idx = t; idx < 64 * CH; idx += 256) {
            const int row = idx / CH, ch = idx % CH;
            h8f val = {0, 0, 0, 0, 0, 0, 0, 0};
            if (bn + row < NN)
                val = reinterpret_cast<const h8f*>(xh + (size_t)(bn + row) * K)[ch];
            *reinterpret_cast<h8f*>(&xs[row * PADK + ch * 8]) = val;
        }
    }
    // stage this block's weight matrix (h8f: 16B per thread-iter)
    {
        const h8f* __restrict__ wg = reinterpret_cast<const h8f*>(wshuf + (size_t)m * K * 128);
        h8f* __restrict__ wl8 = reinterpret_cast<h8f*>(wt);
        constexpr int WH8 = K * 16;
        for (int idx = t; idx < WH8; idx += 256) wl8[idx] = wg[idx];
    }
    __syncthreads();

    const int wid = t >> 6, lane = t & 63;
    const int rloc = wid * 16 + (lane & 15);
    const int ko = (lane >> 4) * 4;
    h4f b[KS];
#pragma unroll
    for (int s = 0; s < KS; ++s)
        b[s] = *reinterpret_cast<const h4f*>(&xs[rloc * PADK + s * 16 + ko]);

    const int node = bn + rloc;
    const int hcq = (lane >> 4) * 4;
    const float* bias[4] = {bq, bk, bv, bs};
    _Float16* outs[4] = {qout, kout, vout, skout};
    const h4f* __restrict__ wl = reinterpret_cast<const h4f*>(wt);

    f32x4 acc[8];
#pragma unroll
    for (int c = 0; c < 8; ++c) acc[c] = {0, 0, 0, 0};
#pragma unroll
    for (int c = 0; c < 8; ++c)
#pragma unroll
        for (int s = 0; s < KS; ++s) {
            h4f af = wl[(s * 8 + c) * 64 + lane];
            acc[c] = __builtin_amdgcn_mfma_f32_16x16x16f16(af, b[s], acc[c], 0, 0, 0);
        }
    if (node < NN) {
        const float* bm = bias[m];
        _Float16* dst = outs[m];
#pragma unroll
        for (int c = 0; c < 8; ++c) {
            const int hc = c * 16 + hcq;
            const float4 bb = *reinterpret_cast<const float4*>(&bm[hc]);
            h4f oh = {(_Float16)(acc[c][0] + bb.x), (_Float16)(acc[c][1] + bb.y),
                      (_Float16)(acc[c][2] + bb.z), (_Float16)(acc[c][3] + bb.w)};
            *reinterpret_cast<h4f*>(&dst[(size_t)node * 128 + hc]) = oh;
        }
    }
}

// ---------------- fused per-node attention aggregation (unchanged control) ----------------
__global__ __launch_bounds__(256, 8) void node_agg(
    const int* __restrict__ rowptr, const int4* __restrict__ edges,
    const _Float16* __restrict__ qh, const _Float16* __restrict__ kh,
    const _Float16* __restrict__ vh, const float* __restrict__ we,
    const _Float16* __restrict__ sk, _Float16* __restrict__ houth, int relu)
{
    __shared__ float we_s[4 * 128];
    const int t = threadIdx.x;
    if (t < 128)
        reinterpret_cast<float4*>(we_s)[t] = reinterpret_cast<const float4*>(we)[t];
    __syncthreads();
    const int node = blockIdx.x * 4 + (t >> 6);
    if (node >= NN) return;
    const int lane = t & 63;
    const int g = lane >> 4, sub = lane & 15, ch0 = sub * 8;
    const int beg = rowptr[node], end = rowptr[node + 1];
    const int deg = end - beg;

    const float sc = 0.17677669529663687f * 1.4426950408889634f;
    const h8f q8 = *reinterpret_cast<const h8f*>(&qh[(size_t)node * 128 + ch0]);
    float qf[8];
#pragma unroll
    for (int j = 0; j < 8; ++j) qf[j] = (float)q8[j] * sc;
    h2f qp[4];
#pragma unroll
    for (int i = 0; i < 4; ++i) {
        qp[i][0] = (_Float16)qf[2 * i];
        qp[i][1] = (_Float16)qf[2 * i + 1];
    }

    float qe[4];
#pragma unroll
    for (int d = 0; d < 4; ++d) {
        const float4 wa = *reinterpret_cast<const float4*>(&we_s[d * 128 + ch0]);
        const float4 wb = *reinterpret_cast<const float4*>(&we_s[d * 128 + ch0 + 4]);
        float pq = wa.x * qf[0] + wa.y * qf[1] + wa.z * qf[2] + wa.w * qf[3]
                 + wb.x * qf[4] + wb.y * qf[5] + wb.z * qf[6] + wb.w * qf[7];
        pq += __shfl_xor(pq, 1); pq += __shfl_xor(pq, 2);
        qe[d] = pq;
    }

    float m = -1e30f, s = 0.f;
    float acc[8] = {0, 0, 0, 0, 0, 0, 0, 0};
    float T[4] = {0, 0, 0, 0};

    const int nt = (deg + 3) >> 2;
    int p = beg + g;
    for (int i = 0; i < nt; ++i, p += 4) {
        const bool act = p < end;
        const int4 r = edges[act ? p : beg];
        const int4 ki = *reinterpret_cast<const int4*>(&kh[(size_t)r.x * 128 + ch0]);
        const int4 vi = *reinterpret_cast<const int4*>(&vh[(size_t)r.x * 128 + ch0]);
        float al = FDOT2(qp[0], __builtin_bit_cast(h2f, ki.x), 0.0f);
        al = FDOT2(qp[1], __builtin_bit_cast(h2f, ki.y), al);
        al = FDOT2(qp[2], __builtin_bit_cast(h2f, ki.z), al);
        al = FDOT2(qp[3], __builtin_bit_cast(h2f, ki.w), al);
        al += __shfl_xor(al, 1); al += __shfl_xor(al, 2);
        const h2f e01 = __builtin_bit_cast(h2f, r.y);
        const h2f e23 = __builtin_bit_cast(h2f, r.z);
        const float f0 = (float)e01[0], f1 = (float)e01[1];
        const float f2 = (float)e23[0], f3 = (float)e23[1];
        al += f0 * qe[0] + f1 * qe[1] + f2 * qe[2] + f3 * qe[3];
        al = act ? al : -1e30f;
        if (__any(al > m + 10.0f)) {
            const float mn = fmaxf(m, al);
            const float rr = exp2f(m - mn);
            s *= rr;
#pragma unroll
            for (int j = 0; j < 8; ++j) acc[j] *= rr;
#pragma unroll
            for (int d = 0; d < 4; ++d) T[d] *= rr;
            m = mn;
        }
        const float pe = exp2f(al - m);
        s += pe;
        const h2f v01 = __builtin_bit_cast(h2f, vi.x);
        const h2f v23 = __builtin_bit_cast(h2f, vi.y);
        const h2f v45 = __builtin_bit_cast(h2f, vi.z);
        const h2f v67 = __builtin_bit_cast(h2f, vi.w);
        acc[0] += pe * (float)v01[0]; acc[1] += pe * (float)v01[1];
        acc[2] += pe * (float)v23[0]; acc[3] += pe * (float)v23[1];
        acc[4] += pe * (float)v45[0]; acc[5] += pe * (float)v45[1];
        acc[6] += pe * (float)v67[0]; acc[7] += pe * (float)v67[1];
        T[0] += pe * f0; T[1] += pe * f1; T[2] += pe * f2; T[3] += pe * f3;
    }

#pragma unroll
    for (int off = 16; off <= 32; off <<= 1) {
        const float mo = __shfl_xor(m, off);
        const float so = __shfl_xor(s, off);
        const float mn = fmaxf(m, mo);
        const float r1 = exp2f(m - mn), r2 = exp2f(mo - mn);
        s = s * r1 + so * r2;
#pragma unroll
        for (int j = 0; j < 8; ++j) {
            const float ao = __shfl_xor(acc[j], off);
            acc[j] = acc[j] * r1 + ao * r2;
        }
#pragma unroll
        for (int d = 0; d < 4; ++d) {
            const float To = __shfl_xor(T[d], off);
            T[d] = T[d] * r1 + To * r2;
        }
        m = mn;
    }

    if (g == 0) {
        const float inv = 1.0f / (s + 1e-16f);
        float4 wa[4], wb[4];
#pragma unroll
        for (int d = 0; d < 4; ++d) {
            wa[d] = *reinterpret_cast<const float4*>(&we_s[d * 128 + ch0]);
            wb[d] = *reinterpret_cast<const float4*>(&we_s[d * 128 + ch0 + 4]);
        }
        const h8f sk8 = *reinterpret_cast<const h8f*>(&sk[(size_t)node * 128 + ch0]);
        float ov[8];
        ov[0] = (acc[0] + wa[0].x * T[0] + wa[1].x * T[1] + wa[2].x * T[2] + wa[3].x * T[3]) * inv + (float)sk8[0];
        ov[1] = (acc[1] + wa[0].y * T[0] + wa[1].y * T[1] + wa[2].y * T[2] + wa[3].y * T[3]) * inv + (float)sk8[1];
        ov[2] = (acc[2] + wa[0].z * T[0] + wa[1].z * T[1] + wa[2].z * T[2] + wa[3].z * T[3]) * inv + (float)sk8[2];
        ov[3] = (acc[3] + wa[0].w * T[0] + wa[1].w * T[1] + wa[2].w * T[2] + wa[3].w * T[3]) * inv + (float)sk8[3];
        ov[4] = (acc[4] + wb[0].x * T[0] + wb[1].x * T[1] + wb[2].x * T[2] + wb[3].x * T[3]) * inv + (float)sk8[4];
        ov[5] = (acc[5] + wb[0].y * T[0] + wb[1].y * T[1] + wb[2].y * T[2] + wb[3].y * T[3]) * inv + (float)sk8[5];
        ov[6] = (acc[6] + wb[0].z * T[0] + wb[1].z * T[1] + wb[2].z * T[2] + wb[3].z * T[3]) * inv + (float)sk8[6];
        ov[7] = (acc[7] + wb[0].w * T[0] + wb[1].w * T[1] + wb[2].w * T[2] + wb[3].w * T[3]) * inv + (float)sk8[7];
        h8f oh;
#pragma unroll
        for (int j = 0; j < 8; ++j) {
            float v = relu ? fmaxf(ov[j], 0.f) : ov[j];
            oh[j] = (_Float16)v;
        }
        *reinterpret_cast<h8f*>(&houth[(size_t)node * 128 + ch0]) = oh;
    }
}

// ---------------- pooling + head (batch is sorted; h in f16) ----------------

__global__ __launch_bounds__(128) void head_k(
    const _Float16* __restrict__ h, const int* __restrict__ gptr,
    const float* __restrict__ wlin, const float* __restrict__ blin,
    float* __restrict__ out)
{
    __shared__ float red[128];
    const int g = blockIdx.x;
    const int t = threadIdx.x;
    const int beg = gptr[g], end = gptr[g + 1];
    float p = 0.f;
    for (int n = beg; n < end; ++n) p += (float)h[(size_t)n * 128 + t];
    p *= wlin[t];
    red[t] = p;
    __syncthreads();
    for (int off = 64; off; off >>= 1) {
        if (t < off) red[t] += red[t + off];
        __syncthreads();
    }
    if (t == 0) out[g] = red[0] / fmaxf((float)(end - beg), 1.0f) + blin[0];
}

extern "C" void kernel_launch(void* const* d_in, const int* in_sizes, int n_in,
                              void* d_out, int out_size, void* d_ws, size_t ws_size,
                              hipStream_t stream)
{
    const float* x     = (const float*)d_in[0];
    const int*   ei    = (const int*)d_in[1];
    const float* ea    = (const float*)d_in[2];
    const int*   batch = (const int*)d_in[3];
    auto W = [&](int i) { return (const float*)d_in[i]; };

    char* wsb = (char*)d_ws;
    size_t off = 0;
    auto alloc = [&](size_t bytes) { void* p = wsb + off; off += (bytes + 15) & ~15ull; return p; };

    int4*  edges    = (int4*)alloc((size_t)EE * 16);
    _Float16* qh    = (_Float16*)alloc((size_t)NN * 128 * 2);
    _Float16* kh    = (_Float16*)alloc((size_t)NN * 128 * 2);
    _Float16* vh    = (_Float16*)alloc((size_t)NN * 128 * 2);
    _Float16* sk    = (_Float16*)alloc((size_t)NN * 128 * 2);
    _Float16* hh    = (_Float16*)alloc((size_t)NN * 128 * 2);
    _Float16* wshuf = (_Float16*)alloc(((size_t)4 * 64 * 128 + 8 * 128 * 128) * 2);
    int* cnt    = (int*)alloc((size_t)NN * 4);
    int* rowptr = (int*)alloc((size_t)(NN + 1) * 4);
    int* wcur   = (int*)alloc((size_t)NN * 4);
    int* gptr   = (int*)alloc((size_t)(GG + 1) * 4);
    int* bsum   = (int*)alloc((size_t)64 * 4);

    // ---- CSR build + packed edge records (recomputed each call; deterministic) ----
    hipMemsetAsync(cnt, 0, NN * sizeof(int), stream);
    hist_k<<<ceil_div(EE, 256), 256, 0, stream>>>(ei, cnt);
    const int NB = ceil_div(NN, 1024);
    scan1_k<<<NB, 1024, 0, stream>>>(cnt, NN, rowptr, bsum, batch, gptr);
    scan3_k<<<NB, 1024, 0, stream>>>(rowptr, wcur, bsum, NN);
    scatter_k<<<ceil_div(EE, 256), 256, 0, stream>>>(ei, (const float4*)ea, wcur, edges);

    W12 w12 = {{ W(4), W(6), W(8), W(11),
                 W(13), W(15), W(17), W(20),
                 W(22), W(24), W(26), W(29) }};
    shuffle_w12<<<dim3(64, 12), 64, 0, stream>>>(w12, wshuf);
    const size_t wsz1 = (size_t)4 * 64 * 128;
    const size_t wsz2 = (size_t)4 * 128 * 128;

    auto layer = [&](int K, const void* xin, const _Float16* wsh, int relu, int wb) {
        dim3 gg(ceil_div(NN, 64), 4);
        if (K == 64)
            gemm_mfma<64, true><<<gg, 256, 0, stream>>>(
                xin, wsh, W(wb + 1), W(wb + 3), W(wb + 5), W(wb + 8), qh, kh, vh, sk);
        else
            gemm_mfma<128, false><<<gg, 256, 0, stream>>>(
                xin, wsh, W(wb + 1), W(wb + 3), W(wb + 5), W(wb + 8), qh, kh, vh, sk);
        node_agg<<<ceil_div(NN, 4), 256, 0, stream>>>(
            rowptr, edges, qh, kh, vh, W(wb + 6), sk, hh, relu);
    };

    layer(64,  x,  wshuf, 1, 4);
    layer(128, hh, wshuf + wsz1, 1, 13);
    layer(128, hh, wshuf + wsz1 + wsz2, 0, 22);

    head_k<<<GG, 128, 0, stream>>>(hh, gptr, W(31), W(32), (float*)d_out);
}